// Round 2
// baseline (6119.340 us; speedup 1.0000x reference)
//
#include <hip/hip_runtime.h>
#include <hip/hip_bf16.h>
#include <math.h>

// Problem constants
#define BB 32
#define LL 1024
#define C_IN 21
#define DM 256
#define DFF 1024
#define NLAYERS 3
#define TOPK 6
#define FFN_CHUNK 4096

__device__ __forceinline__ float gelu_f(float v){
    return 0.5f * v * (1.0f + erff(v * 0.7071067811865476f));
}

// ---------------- token embedding: circular conv1d k=3 ----------------
__global__ __launch_bounds__(256) void token_embed_k(const float* __restrict__ x,
                                                     const float* __restrict__ w,
                                                     float* __restrict__ out){
    int bl = blockIdx.x;
    int b = bl / LL, l = bl % LL;
    int d = threadIdx.x;
    __shared__ float xs[3][C_IN];
    if (threadIdx.x < 3*C_IN){
        int j = threadIdx.x / C_IN, c = threadIdx.x % C_IN;
        int ll = l + j - 1;
        ll = (ll + LL) % LL;
        xs[j][c] = x[(size_t)b*LL*C_IN + (size_t)ll*C_IN + c];
    }
    __syncthreads();
    const float* wd = w + (size_t)d*C_IN*3;
    float acc = 0.f;
    #pragma unroll
    for (int c=0;c<C_IN;c++){
        #pragma unroll
        for (int j=0;j<3;j++)
            acc += xs[j][c] * wd[c*3+j];
    }
    out[(size_t)bl*DM + d] = acc;
}

// ---------------- generic SGEMM: C(M,N) = A(M,K) @ W(N,K)^T [+bias] [gelu] ----------------
template<bool BIAS, bool GELU>
__global__ __launch_bounds__(256) void gemm_tn(const float* __restrict__ A,
                                               const float* __restrict__ W,
                                               const float* __restrict__ bias,
                                               float* __restrict__ C,
                                               int M, int N, int K){
    __shared__ float As[16][68];
    __shared__ float Bs[16][68];
    int bm = blockIdx.x*64, bn = blockIdx.y*64;
    int tid = threadIdx.x;
    int tm = (tid>>4)<<2, tn = (tid&15)<<2;
    float acc[4][4] = {};
    for (int k0=0;k0<K;k0+=16){
        #pragma unroll
        for (int i=0;i<4;i++){
            int idx = tid + i*256;
            int r = idx>>4, c = idx&15;
            As[c][r] = A[(size_t)(bm+r)*K + k0 + c];
            Bs[c][r] = W[(size_t)(bn+r)*K + k0 + c];
        }
        __syncthreads();
        #pragma unroll
        for (int kk=0;kk<16;kk++){
            float a0=As[kk][tm],a1=As[kk][tm+1],a2=As[kk][tm+2],a3=As[kk][tm+3];
            float b0=Bs[kk][tn],b1=Bs[kk][tn+1],b2=Bs[kk][tn+2],b3=Bs[kk][tn+3];
            acc[0][0]+=a0*b0; acc[0][1]+=a0*b1; acc[0][2]+=a0*b2; acc[0][3]+=a0*b3;
            acc[1][0]+=a1*b0; acc[1][1]+=a1*b1; acc[1][2]+=a1*b2; acc[1][3]+=a1*b3;
            acc[2][0]+=a2*b0; acc[2][1]+=a2*b1; acc[2][2]+=a2*b2; acc[2][3]+=a2*b3;
            acc[3][0]+=a3*b0; acc[3][1]+=a3*b1; acc[3][2]+=a3*b2; acc[3][3]+=a3*b3;
        }
        __syncthreads();
    }
    #pragma unroll
    for (int i=0;i<4;i++){
        #pragma unroll
        for (int j=0;j<4;j++){
            float v = acc[i][j];
            if (BIAS) v += bias[bn+tn+j];
            if (GELU) v = gelu_f(v);
            C[(size_t)(bm+tm+i)*N + (bn+tn+j)] = v;
        }
    }
}

// ---------------- correlation: mean_corr[b,t] = (1/256) sum_{(i-j)%L==t} Q[b,i,:]·K[b,j,:] ----------------
__global__ __launch_bounds__(256) void corr_kernel(const float* __restrict__ q,
                                                   const float* __restrict__ k,
                                                   float* __restrict__ mc){
    __shared__ float Qs[16][68];
    __shared__ float Ks[16][68];
    __shared__ float bins[127];
    int b = blockIdx.z;
    int bi = blockIdx.x*64, bj = blockIdx.y*64;
    int tid = threadIdx.x;
    for (int i=tid;i<127;i+=256) bins[i]=0.f;
    int ti = (tid>>4)<<2, tj = (tid&15)<<2;
    float acc[4][4] = {};
    const float* qb = q + (size_t)b*LL*DM;
    const float* kb = k + (size_t)b*LL*DM;
    for (int k0=0;k0<DM;k0+=16){
        #pragma unroll
        for (int i=0;i<4;i++){
            int idx = tid + i*256;
            int r = idx>>4, c = idx&15;
            Qs[c][r] = qb[(size_t)(bi+r)*DM + k0 + c];
            Ks[c][r] = kb[(size_t)(bj+r)*DM + k0 + c];
        }
        __syncthreads();
        #pragma unroll
        for (int kk=0;kk<16;kk++){
            float a0=Qs[kk][ti],a1=Qs[kk][ti+1],a2=Qs[kk][ti+2],a3=Qs[kk][ti+3];
            float b0=Ks[kk][tj],b1=Ks[kk][tj+1],b2=Ks[kk][tj+2],b3=Ks[kk][tj+3];
            acc[0][0]+=a0*b0; acc[0][1]+=a0*b1; acc[0][2]+=a0*b2; acc[0][3]+=a0*b3;
            acc[1][0]+=a1*b0; acc[1][1]+=a1*b1; acc[1][2]+=a1*b2; acc[1][3]+=a1*b3;
            acc[2][0]+=a2*b0; acc[2][1]+=a2*b1; acc[2][2]+=a2*b2; acc[2][3]+=a2*b3;
            acc[3][0]+=a3*b0; acc[3][1]+=a3*b1; acc[3][2]+=a3*b2; acc[3][3]+=a3*b3;
        }
        __syncthreads();
    }
    #pragma unroll
    for (int i=0;i<4;i++)
        #pragma unroll
        for (int j=0;j<4;j++)
            atomicAdd(&bins[(ti+i)-(tj+j)+63], acc[i][j]);
    __syncthreads();
    for (int i=tid;i<127;i+=256){
        int t = ((bi - bj + i - 63) + 2048) & (LL-1);
        atomicAdd(&mc[(size_t)b*LL + t], bins[i] * (1.f/256.f));
    }
}

// ---------------- top-6 + softmax per batch ----------------
__global__ __launch_bounds__(256) void topk_kernel(const float* __restrict__ mc,
                                                   int* __restrict__ delays,
                                                   float* __restrict__ wts){
    int b = blockIdx.x, tid = threadIdx.x;
    __shared__ float sv[LL];
    __shared__ float rv[256];
    __shared__ int ri[256];
    __shared__ float topv[TOPK];
    __shared__ int topi[TOPK];
    for (int i=tid;i<LL;i+=256) sv[i] = mc[(size_t)b*LL + i];
    __syncthreads();
    for (int it=0; it<TOPK; it++){
        float best = -1e30f; int bi = LL;
        for (int i=tid;i<LL;i+=256){
            float v = sv[i];
            if (v > best || (v == best && i < bi)){ best = v; bi = i; }
        }
        rv[tid]=best; ri[tid]=bi;
        __syncthreads();
        for (int s=128;s>0;s>>=1){
            if (tid < s){
                if (rv[tid+s] > rv[tid] || (rv[tid+s]==rv[tid] && ri[tid+s]<ri[tid])){
                    rv[tid]=rv[tid+s]; ri[tid]=ri[tid+s];
                }
            }
            __syncthreads();
        }
        if (tid==0){ topv[it]=rv[0]; topi[it]=ri[0]; sv[ri[0]] = -1e30f; }
        __syncthreads();
    }
    if (tid==0){
        float mx = topv[0];
        float e[TOPK], se=0.f;
        for (int kk=0;kk<TOPK;kk++){ e[kk]=expf(topv[kk]-mx); se+=e[kk]; }
        for (int kk=0;kk<TOPK;kk++){
            wts[b*TOPK+kk] = e[kk]/se;
            delays[b*TOPK+kk] = topi[kk];
        }
    }
}

// ---------------- attention gather: a[b,l,d] = sum_k w[b,k]*v[b,(l+delay)%L,d] ----------------
__global__ __launch_bounds__(256) void attn_gather(const float* __restrict__ v,
                                                   const int* __restrict__ delays,
                                                   const float* __restrict__ wts,
                                                   float* __restrict__ a){
    int bl = blockIdx.x;
    int b = bl / LL, l = bl % LL;
    int d = threadIdx.x;
    __shared__ int dl[TOPK];
    __shared__ float w[TOPK];
    if (threadIdx.x < TOPK){
        dl[threadIdx.x] = delays[b*TOPK+threadIdx.x];
        w[threadIdx.x]  = wts[b*TOPK+threadIdx.x];
    }
    __syncthreads();
    float acc = 0.f;
    #pragma unroll
    for (int kk=0;kk<TOPK;kk++){
        int ls = (l + dl[kk]) & (LL-1);
        acc += w[kk] * v[((size_t)b*LL + ls)*DM + d];
    }
    a[(size_t)bl*DM + d] = acc;
}

// ---------------- out = (xa+xb) - movmean5(xa+xb), clamped edges ----------------
__global__ __launch_bounds__(256) void add_decomp(const float* __restrict__ xa,
                                                  const float* __restrict__ xb,
                                                  float* __restrict__ out){
    int b = blockIdx.x, l0 = blockIdx.y*32;
    int d = threadIdx.x;
    __shared__ float s[36][DM];
    for (int j=0;j<36;j++){
        int g = l0 - 2 + j;
        g = g < 0 ? 0 : (g > LL-1 ? LL-1 : g);
        size_t idx = ((size_t)b*LL + g)*DM + d;
        s[j][d] = xa[idx] + xb[idx];
    }
    __syncthreads();
    for (int i=0;i<32;i++){
        float m = (s[i][d]+s[i+1][d]+s[i+2][d]+s[i+3][d]+s[i+4][d])*0.2f;
        out[((size_t)b*LL + l0+i)*DM + d] = s[i+2][d] - m;
    }
}

// ---------------- layernorm over d per (b,l) ----------------
__global__ __launch_bounds__(256) void ln_kernel(const float* __restrict__ x,
                                                 const float* __restrict__ nw,
                                                 const float* __restrict__ nb,
                                                 float* __restrict__ xh){
    int bl = blockIdx.x, d = threadIdx.x;
    float val = x[(size_t)bl*DM + d];
    __shared__ float red[4];
    float v = val;
    for (int o=32;o>0;o>>=1) v += __shfl_down(v, o, 64);
    if ((d&63)==0) red[d>>6] = v;
    __syncthreads();
    float mu = (red[0]+red[1]+red[2]+red[3])*(1.f/256.f);
    __syncthreads();
    float diff = val - mu;
    v = diff*diff;
    for (int o=32;o>0;o>>=1) v += __shfl_down(v, o, 64);
    if ((d&63)==0) red[d>>6] = v;
    __syncthreads();
    float var = (red[0]+red[1]+red[2]+red[3])*(1.f/256.f);
    xh[(size_t)bl*DM + d] = diff*rsqrtf(var+1e-5f)*nw[d] + nb[d];
}

// ---------------- column sums over l ----------------
__global__ __launch_bounds__(256) void colsum_kernel(const float* __restrict__ xh,
                                                     float* __restrict__ colsum){
    int b = blockIdx.x, chunk = blockIdx.y, d = threadIdx.x;
    float s = 0.f;
    for (int l = chunk*128; l < (chunk+1)*128; l++)
        s += xh[((size_t)b*LL + l)*DM + d];
    atomicAdd(&colsum[b*DM + d], s);
}

// ---------------- g = gelu(xh - colmean) ----------------
__global__ __launch_bounds__(256) void gelu_sub_kernel(const float* __restrict__ xh,
                                                       const float* __restrict__ colsum,
                                                       float* __restrict__ g){
    int bl = blockIdx.x, d = threadIdx.x;
    int b = bl / LL;
    float v = xh[(size_t)bl*DM + d] - colsum[b*DM + d]*(1.f/1024.f);
    g[(size_t)bl*DM + d] = gelu_f(v);
}

// ---------------- final projection ----------------
__global__ __launch_bounds__(256) void proj_kernel(const float* __restrict__ g,
                                                   const float* __restrict__ pw,
                                                   const float* __restrict__ pb,
                                                   float* __restrict__ out){
    int b = blockIdx.x, c = blockIdx.y, ch = blockIdx.z;
    int tid = threadIdx.x;
    const size_t F = (size_t)LL*DM;
    size_t base = ch*(F/16);
    float s = 0.f;
    for (size_t i = tid; i < F/16; i += 256)
        s += g[(size_t)b*F + base + i] * pw[(size_t)c*F + base + i];
    for (int o=32;o>0;o>>=1) s += __shfl_down(s, o, 64);
    __shared__ float red[4];
    if ((tid&63)==0) red[tid>>6] = s;
    __syncthreads();
    if (tid==0){
        float tot = red[0]+red[1]+red[2]+red[3];
        if (ch==0) tot += pb[c];
        atomicAdd(&out[b*3 + c], tot);
    }
}

extern "C" void kernel_launch(void* const* d_in, const int* in_sizes, int n_in,
                              void* d_out, int out_size, void* d_ws, size_t ws_size,
                              hipStream_t stream) {
    const float* x_enc   = (const float*)d_in[0];
    const float* token_w = (const float*)d_in[1];
    const float* qw = (const float*)d_in[2];
    const float* qb = (const float*)d_in[3];
    const float* kw = (const float*)d_in[4];
    const float* kb = (const float*)d_in[5];
    const float* vw = (const float*)d_in[6];
    const float* vb = (const float*)d_in[7];
    const float* ow = (const float*)d_in[8];
    const float* ob = (const float*)d_in[9];
    const float* c1w = (const float*)d_in[10];
    const float* c2w = (const float*)d_in[11];
    const float* norm_w = (const float*)d_in[12];
    const float* norm_b = (const float*)d_in[13];
    const float* proj_w = (const float*)d_in[14];
    const float* proj_b = (const float*)d_in[15];
    float* outp = (float*)d_out;

    // Workspace layout (floats):
    //   buf0: NTOK (x)                 [32 MiB]
    //   buf1: NTOK                     [32 MiB]
    //   buf2: NTOK                     [32 MiB]
    //   bufY: FFN_CHUNK*DFF            [16 MiB]
    //   mc:   BB*LL, colsum: BB*DM, delays/wts: tiny
    // total ~= 116 MiB
    const size_t NTOK = (size_t)BB*LL*DM;       // 8388608
    float* ws = (float*)d_ws;
    float* buf0 = ws;
    float* buf1 = ws + NTOK;
    float* buf2 = ws + 2*NTOK;
    float* bufY = ws + 3*NTOK;
    float* mc     = bufY + (size_t)FFN_CHUNK*DFF;
    float* colsum = mc + (size_t)BB*LL;
    int*   delays = (int*)(colsum + BB*DM);
    float* wts    = (float*)(delays + BB*TOPK);

    hipMemsetAsync(d_out, 0, 96*sizeof(float), stream);

    token_embed_k<<<BB*LL, 256, 0, stream>>>(x_enc, token_w, buf0);

    const int M = BB*LL; // 32768
    for (int l=0; l<NLAYERS; l++){
        const float* qw_l = qw + (size_t)l*DM*DM;
        const float* qb_l = qb + (size_t)l*DM;
        const float* kw_l = kw + (size_t)l*DM*DM;
        const float* kb_l = kb + (size_t)l*DM;
        const float* vw_l = vw + (size_t)l*DM*DM;
        const float* vb_l = vb + (size_t)l*DM;
        const float* ow_l = ow + (size_t)l*DM*DM;
        const float* ob_l = ob + (size_t)l*DM;
        const float* c1w_l = c1w + (size_t)l*DFF*DM;
        const float* c2w_l = c2w + (size_t)l*DM*DFF;

        // q -> buf1, k -> buf2
        gemm_tn<true,false><<<dim3(M/64, DM/64), 256, 0, stream>>>(buf0, qw_l, qb_l, buf1, M, DM, DM);
        gemm_tn<true,false><<<dim3(M/64, DM/64), 256, 0, stream>>>(buf0, kw_l, kb_l, buf2, M, DM, DM);

        // mean_corr via Gram diagonal sums; top-k
        hipMemsetAsync(mc, 0, (size_t)BB*LL*sizeof(float), stream);
        corr_kernel<<<dim3(LL/64, LL/64, BB), 256, 0, stream>>>(buf1, buf2, mc);
        topk_kernel<<<BB, 256, 0, stream>>>(mc, delays, wts);

        // v -> buf1 (q dead), a -> buf2 (k dead), o -> buf1 (v dead)
        gemm_tn<true,false><<<dim3(M/64, DM/64), 256, 0, stream>>>(buf0, vw_l, vb_l, buf1, M, DM, DM);
        attn_gather<<<BB*LL, 256, 0, stream>>>(buf1, delays, wts, buf2);
        gemm_tn<true,false><<<dim3(M/64, DM/64), 256, 0, stream>>>(buf2, ow_l, ob_l, buf1, M, DM, DM);

        // x1 = (x + o) - movmean -> buf2
        add_decomp<<<dim3(BB, LL/32), 256, 0, stream>>>(buf0, buf1, buf2);

        // FFN in row chunks: y = gelu(x1 @ c1w^T) -> bufY ; y2 = y @ c2w^T -> buf1
        for (int c0 = 0; c0 < M; c0 += FFN_CHUNK){
            gemm_tn<false,true><<<dim3(FFN_CHUNK/64, DFF/64), 256, 0, stream>>>(
                buf2 + (size_t)c0*DM, c1w_l, nullptr, bufY, FFN_CHUNK, DFF, DM);
            gemm_tn<false,false><<<dim3(FFN_CHUNK/64, DM/64), 256, 0, stream>>>(
                bufY, c2w_l, nullptr, buf1 + (size_t)c0*DM, FFN_CHUNK, DM, DFF);
        }

        // x = (x1 + y2) - movmean -> buf0
        add_decomp<<<dim3(BB, LL/32), 256, 0, stream>>>(buf2, buf1, buf0);
    }

    // final layernorm (xh -> buf1)
    ln_kernel<<<BB*LL, 256, 0, stream>>>(buf0, norm_w, norm_b, buf1);
    hipMemsetAsync(colsum, 0, (size_t)BB*DM*sizeof(float), stream);
    colsum_kernel<<<dim3(BB, 8), 256, 0, stream>>>(buf1, colsum);
    // g = gelu(xh - colmean) -> buf2
    gelu_sub_kernel<<<BB*LL, 256, 0, stream>>>(buf1, colsum, buf2);
    // projection
    proj_kernel<<<dim3(BB, 3, 16), 256, 0, stream>>>(buf2, proj_w, proj_b, outp);
}

// Round 6
// 2974.719 us; speedup vs baseline: 2.0571x; 2.0571x over previous
//
#include <hip/hip_runtime.h>
#include <hip/hip_bf16.h>
#include <math.h>

// Problem constants
#define BB 32
#define LL 1024
#define C_IN 21
#define DM 256
#define DFF 1024
#define NLAYERS 3
#define TOPK 6
#define LSCALE 4096.0f
#define LINV (1.0f/4096.0f)

typedef __attribute__((ext_vector_type(8))) short short8v;
typedef __attribute__((ext_vector_type(8))) _Float16 half8;
typedef __attribute__((ext_vector_type(4))) float f32x4;

__device__ __forceinline__ float gelu_f(float v){
    return 0.5f * v * (1.0f + erff(v * 0.7071067811865476f));
}
__device__ __forceinline__ ushort f2h_bits(float f){
    _Float16 h = (_Float16)f;
    return __builtin_bit_cast(ushort, h);
}

// ---------------- weight conversion: f16 hi + 4096*lo ----------------
__global__ __launch_bounds__(256) void split_w_k(const float* __restrict__ src,
                                                 ushort* __restrict__ h, ushort* __restrict__ l, int n){
    int i = blockIdx.x*256 + threadIdx.x;
    if (i < n){
        float f = src[i];
        _Float16 hh = (_Float16)f;
        h[i] = __builtin_bit_cast(ushort, hh);
        l[i] = f2h_bits((f - (float)hh) * LSCALE);
    }
}

// ---------------- token embedding: circular conv1d k=3 ----------------
__global__ __launch_bounds__(256) void token_embed_k(const float* __restrict__ x,
                                                     const float* __restrict__ w,
                                                     float* __restrict__ out){
    int bl = blockIdx.x;
    int b = bl / LL, l = bl % LL;
    int d = threadIdx.x;
    __shared__ float xs[3][C_IN];
    if (threadIdx.x < 3*C_IN){
        int j = threadIdx.x / C_IN, c = threadIdx.x % C_IN;
        int ll = l + j - 1;
        ll = (ll + LL) % LL;
        xs[j][c] = x[(size_t)b*LL*C_IN + (size_t)ll*C_IN + c];
    }
    __syncthreads();
    const float* wd = w + (size_t)d*C_IN*3;
    float acc = 0.f;
    #pragma unroll
    for (int c=0;c<C_IN;c++){
        #pragma unroll
        for (int j=0;j<3;j++)
            acc += xs[j][c] * wd[c*3+j];
    }
    out[(size_t)bl*DM + d] = acc;
}

// =================== split-f16 MFMA GEMM ===================
// C(M,N) = A(M,K) @ W(N,K)^T [+bias] [gelu], accurate to ~5e-7 relative.
// AMODE: 0 = A is f32 (split-staged on the fly), 2 = A is split pair (Av=hi, Av2=4096*lo).
// OMODE: 0 = f32 out, 2 = split pair out (Cv=hi, C2v=4096*lo).
// acc = hi*hi' ; accX = hi*lo' + lo*hi' (scaled 4096); C = acc + accX/4096.
template<int AMODE, bool BIAS, bool GELU, int OMODE>
__global__ __launch_bounds__(256) void gemm_mfma_split(const void* __restrict__ Av,
                                                       const void* __restrict__ Av2,
                                                       const ushort* __restrict__ Wh,
                                                       const ushort* __restrict__ Wl,
                                                       const float* __restrict__ bias,
                                                       void* __restrict__ Cv,
                                                       void* __restrict__ C2v,
                                                       int M, int N, int K){
    __shared__ __align__(16) ushort Ah_s[128*32];
    __shared__ __align__(16) ushort Al_s[128*32];
    __shared__ __align__(16) ushort Wh_s[128*32];
    __shared__ __align__(16) ushort Wl_s[128*32];

    const int tid = threadIdx.x;
    const int MB = M >> 7;
    const int bx = blockIdx.x % MB, by = blockIdx.x / MB;
    const int bm = bx << 7, bn = by << 7;

    const int lane = tid & 63;
    const int wid  = tid >> 6;
    const int wm = wid >> 1, wn = wid & 1;
    const int lr = lane & 15, lg = lane >> 4;

    int aoff[4], boff[4];
    #pragma unroll
    for (int f=0; f<4; f++){
        int ar = wm*64 + f*16 + lr;
        aoff[f] = ar*32 + (lg ^ ((ar>>1)&3))*8;
        int br = wn*64 + f*16 + lr;
        boff[f] = br*32 + (lg ^ ((br>>1)&3))*8;
    }

    f32x4 acc[4][4], accX[4][4];
    #pragma unroll
    for (int i=0;i<4;i++)
        #pragma unroll
        for (int j=0;j<4;j++){
            acc[i][j]  = (f32x4){0.f,0.f,0.f,0.f};
            accX[i][j] = (f32x4){0.f,0.f,0.f,0.f};
        }

    for (int k0=0; k0<K; k0+=32){
        // ---- stage A (hi+lo) ----
        #pragma unroll
        for (int i=0;i<2;i++){
            int c = tid*2 + i;
            int row = c >> 2, ko = c & 3;
            int sw = ko ^ ((row>>1)&3);
            int dst = row*32 + sw*8;
            if (AMODE == 2){
                const ushort* Ah_g = (const ushort*)Av;
                const ushort* Al_g = (const ushort*)Av2;
                size_t src = (size_t)(bm+row)*K + k0 + ko*8;
                *reinterpret_cast<short8v*>(&Ah_s[dst]) = *reinterpret_cast<const short8v*>(Ah_g + src);
                *reinterpret_cast<short8v*>(&Al_s[dst]) = *reinterpret_cast<const short8v*>(Al_g + src);
            } else {
                const float* A = (const float*)Av;
                const float* p = A + (size_t)(bm+row)*K + k0 + ko*8;
                float4 f0 = *reinterpret_cast<const float4*>(p);
                float4 f1 = *reinterpret_cast<const float4*>(p+4);
                float vals[8] = {f0.x,f0.y,f0.z,f0.w,f1.x,f1.y,f1.z,f1.w};
                short8v hv, lv;
                #pragma unroll
                for (int j=0;j<8;j++){
                    _Float16 hh = (_Float16)vals[j];
                    hv[j] = (short)__builtin_bit_cast(ushort, hh);
                    lv[j] = (short)f2h_bits((vals[j] - (float)hh) * LSCALE);
                }
                *reinterpret_cast<short8v*>(&Ah_s[dst]) = hv;
                *reinterpret_cast<short8v*>(&Al_s[dst]) = lv;
            }
        }
        // ---- stage W (hi+lo) ----
        #pragma unroll
        for (int i=0;i<2;i++){
            int c = tid*2 + i;
            int row = c >> 2, ko = c & 3;
            int sw = ko ^ ((row>>1)&3);
            int dst = row*32 + sw*8;
            size_t src = (size_t)(bn+row)*K + k0 + ko*8;
            *reinterpret_cast<short8v*>(&Wh_s[dst]) = *reinterpret_cast<const short8v*>(Wh + src);
            *reinterpret_cast<short8v*>(&Wl_s[dst]) = *reinterpret_cast<const short8v*>(Wl + src);
        }
        __syncthreads();

        short8v af[4], bf_[4], al[4], bl[4];
        #pragma unroll
        for (int f=0; f<4; f++){
            af[f]  = *reinterpret_cast<short8v*>(&Ah_s[aoff[f]]);
            bf_[f] = *reinterpret_cast<short8v*>(&Wh_s[boff[f]]);
            al[f]  = *reinterpret_cast<short8v*>(&Al_s[aoff[f]]);
            bl[f]  = *reinterpret_cast<short8v*>(&Wl_s[boff[f]]);
        }
        #pragma unroll
        for (int i=0;i<4;i++){
            #pragma unroll
            for (int j=0;j<4;j++){
                acc[i][j] = __builtin_amdgcn_mfma_f32_16x16x32_f16(
                    __builtin_bit_cast(half8, af[i]), __builtin_bit_cast(half8, bf_[j]), acc[i][j], 0,0,0);
                accX[i][j] = __builtin_amdgcn_mfma_f32_16x16x32_f16(
                    __builtin_bit_cast(half8, af[i]), __builtin_bit_cast(half8, bl[j]), accX[i][j], 0,0,0);
                accX[i][j] = __builtin_amdgcn_mfma_f32_16x16x32_f16(
                    __builtin_bit_cast(half8, al[i]), __builtin_bit_cast(half8, bf_[j]), accX[i][j], 0,0,0);
            }
        }
        __syncthreads();
    }

    // ---- epilogue ----
    const int crow0 = bm + wm*64, ccol0 = bn + wn*64;
    #pragma unroll
    for (int i=0;i<4;i++){
        #pragma unroll
        for (int j=0;j<4;j++){
            int row0 = crow0 + i*16 + lg*4;
            int col  = ccol0 + j*16 + lr;
            float bv = BIAS ? bias[col] : 0.f;
            #pragma unroll
            for (int r=0;r<4;r++){
                float v = acc[i][j][r] + accX[i][j][r]*LINV + bv;
                if (GELU) v = gelu_f(v);
                size_t idx = (size_t)(row0+r)*N + col;
                if (OMODE == 0){
                    ((float*)Cv)[idx] = v;
                } else {
                    _Float16 hh = (_Float16)v;
                    ((ushort*)Cv)[idx]  = __builtin_bit_cast(ushort, hh);
                    ((ushort*)C2v)[idx] = f2h_bits((v - (float)hh) * LSCALE);
                }
            }
        }
    }
}

// =================== corr: mean_corr via split-f16 MFMA Gram + diagonal binning ===================
__global__ __launch_bounds__(256) void corr_mfma(const ushort* __restrict__ qh,
                                                 const ushort* __restrict__ ql,
                                                 const ushort* __restrict__ kh,
                                                 const ushort* __restrict__ kl,
                                                 float* __restrict__ mc){
    __shared__ __align__(16) ushort Qh_s[128*32];
    __shared__ __align__(16) ushort Ql_s[128*32];
    __shared__ __align__(16) ushort Kh_s[128*32];
    __shared__ __align__(16) ushort Kl_s[128*32];
    __shared__ float bins[255];

    const int tid = threadIdx.x;
    const int b  = blockIdx.z;
    const int bi = blockIdx.x * 128, bj = blockIdx.y * 128;

    for (int i=tid; i<255; i+=256) bins[i] = 0.f;

    const int lane = tid & 63;
    const int wid  = tid >> 6;
    const int wm = wid >> 1, wn = wid & 1;
    const int lr = lane & 15, lg = lane >> 4;

    int aoff[4], boff[4];
    #pragma unroll
    for (int f=0; f<4; f++){
        int ar = wm*64 + f*16 + lr;
        aoff[f] = ar*32 + (lg ^ ((ar>>1)&3))*8;
        int br = wn*64 + f*16 + lr;
        boff[f] = br*32 + (lg ^ ((br>>1)&3))*8;
    }

    f32x4 acc[4][4], accX[4][4];
    #pragma unroll
    for (int i=0;i<4;i++)
        #pragma unroll
        for (int j=0;j<4;j++){
            acc[i][j]  = (f32x4){0.f,0.f,0.f,0.f};
            accX[i][j] = (f32x4){0.f,0.f,0.f,0.f};
        }

    const size_t qbase = (size_t)b*LL*DM;

    for (int k0=0; k0<DM; k0+=32){
        #pragma unroll
        for (int i=0;i<2;i++){
            int c = tid*2 + i;
            int row = c >> 2, ko = c & 3;
            int sw = ko ^ ((row>>1)&3);
            size_t qsrc = qbase + (size_t)(bi+row)*DM + k0 + ko*8;
            size_t ksrc = qbase + (size_t)(bj+row)*DM + k0 + ko*8;
            int dst = row*32 + sw*8;
            *reinterpret_cast<short8v*>(&Qh_s[dst]) = *reinterpret_cast<const short8v*>(qh + qsrc);
            *reinterpret_cast<short8v*>(&Ql_s[dst]) = *reinterpret_cast<const short8v*>(ql + qsrc);
            *reinterpret_cast<short8v*>(&Kh_s[dst]) = *reinterpret_cast<const short8v*>(kh + ksrc);
            *reinterpret_cast<short8v*>(&Kl_s[dst]) = *reinterpret_cast<const short8v*>(kl + ksrc);
        }
        __syncthreads();

        short8v ah[4], al_[4], bh[4], bl_[4];
        #pragma unroll
        for (int f=0; f<4; f++){
            ah[f]  = *reinterpret_cast<short8v*>(&Qh_s[aoff[f]]);
            al_[f] = *reinterpret_cast<short8v*>(&Ql_s[aoff[f]]);
            bh[f]  = *reinterpret_cast<short8v*>(&Kh_s[boff[f]]);
            bl_[f] = *reinterpret_cast<short8v*>(&Kl_s[boff[f]]);
        }
        #pragma unroll
        for (int i=0;i<4;i++){
            #pragma unroll
            for (int j=0;j<4;j++){
                acc[i][j] = __builtin_amdgcn_mfma_f32_16x16x32_f16(
                    __builtin_bit_cast(half8, ah[i]), __builtin_bit_cast(half8, bh[j]), acc[i][j], 0,0,0);
                accX[i][j] = __builtin_amdgcn_mfma_f32_16x16x32_f16(
                    __builtin_bit_cast(half8, ah[i]), __builtin_bit_cast(half8, bl_[j]), accX[i][j], 0,0,0);
                accX[i][j] = __builtin_amdgcn_mfma_f32_16x16x32_f16(
                    __builtin_bit_cast(half8, al_[i]), __builtin_bit_cast(half8, bh[j]), accX[i][j], 0,0,0);
            }
        }
        __syncthreads();
    }

    #pragma unroll
    for (int i=0;i<4;i++){
        #pragma unroll
        for (int j=0;j<4;j++){
            int rbase = wm*64 + i*16 + lg*4;
            int col   = wn*64 + j*16 + lr;
            #pragma unroll
            for (int r=0;r<4;r++){
                float g = acc[i][j][r] + accX[i][j][r] * LINV;
                atomicAdd(&bins[(rbase + r) - col + 127], g);
            }
        }
    }
    __syncthreads();
    for (int i=tid; i<255; i+=256){
        int t = ((bi - bj + i - 127) % LL + LL) & (LL-1);
        atomicAdd(&mc[(size_t)b*LL + t], bins[i] * (1.f/256.f));
    }
}

// ---------------- top-6 + softmax per batch ----------------
__global__ __launch_bounds__(256) void topk_kernel(const float* __restrict__ mc,
                                                   int* __restrict__ delays,
                                                   float* __restrict__ wts){
    int b = blockIdx.x, tid = threadIdx.x;
    __shared__ float sv[LL];
    __shared__ float rv[256];
    __shared__ int ri[256];
    __shared__ float topv[TOPK];
    __shared__ int topi[TOPK];
    for (int i=tid;i<LL;i+=256) sv[i] = mc[(size_t)b*LL + i];
    __syncthreads();
    for (int it=0; it<TOPK; it++){
        float best = -1e30f; int bi = LL;
        for (int i=tid;i<LL;i+=256){
            float v = sv[i];
            if (v > best || (v == best && i < bi)){ best = v; bi = i; }
        }
        rv[tid]=best; ri[tid]=bi;
        __syncthreads();
        for (int s=128;s>0;s>>=1){
            if (tid < s){
                if (rv[tid+s] > rv[tid] || (rv[tid+s]==rv[tid] && ri[tid+s]<ri[tid])){
                    rv[tid]=rv[tid+s]; ri[tid]=ri[tid+s];
                }
            }
            __syncthreads();
        }
        if (tid==0){ topv[it]=rv[0]; topi[it]=ri[0]; sv[ri[0]] = -1e30f; }
        __syncthreads();
    }
    if (tid==0){
        float mx = topv[0];
        float e[TOPK], se=0.f;
        for (int kk=0;kk<TOPK;kk++){ e[kk]=expf(topv[kk]-mx); se+=e[kk]; }
        for (int kk=0;kk<TOPK;kk++){
            wts[b*TOPK+kk] = e[kk]/se;
            delays[b*TOPK+kk] = topi[kk];
        }
    }
}

// ---------------- attention gather (r2-proven scalar) ----------------
__global__ __launch_bounds__(256) void attn_gather(const float* __restrict__ v,
                                                   const int* __restrict__ delays,
                                                   const float* __restrict__ wts,
                                                   float* __restrict__ a){
    int bl = blockIdx.x;
    int b = bl / LL, l = bl % LL;
    int d = threadIdx.x;
    __shared__ int dl[TOPK];
    __shared__ float w[TOPK];
    if (threadIdx.x < TOPK){
        dl[threadIdx.x] = delays[b*TOPK+threadIdx.x];
        w[threadIdx.x]  = wts[b*TOPK+threadIdx.x];
    }
    __syncthreads();
    float acc = 0.f;
    #pragma unroll
    for (int kk=0;kk<TOPK;kk++){
        int ls = (l + dl[kk]) & (LL-1);
        acc += w[kk] * v[((size_t)b*LL + ls)*DM + d];
    }
    a[(size_t)bl*DM + d] = acc;
}

// ---------------- (xa+xb) - movmean5 (r2-proven) ----------------
__global__ __launch_bounds__(256) void add_decomp(const float* __restrict__ xa,
                                                  const float* __restrict__ xb,
                                                  float* __restrict__ out){
    int b = blockIdx.x, l0 = blockIdx.y*32;
    int d = threadIdx.x;
    __shared__ float s[36][DM];
    for (int j=0;j<36;j++){
        int g = l0 - 2 + j;
        g = g < 0 ? 0 : (g > LL-1 ? LL-1 : g);
        size_t idx = ((size_t)b*LL + g)*DM + d;
        s[j][d] = xa[idx] + xb[idx];
    }
    __syncthreads();
    for (int i=0;i<32;i++){
        float m = (s[i][d]+s[i+1][d]+s[i+2][d]+s[i+3][d]+s[i+4][d])*0.2f;
        out[((size_t)b*LL + l0+i)*DM + d] = s[i+2][d] - m;
    }
}

// ---------------- layernorm over d per (b,l) ----------------
__global__ __launch_bounds__(256) void ln_kernel(const float* __restrict__ x,
                                                 const float* __restrict__ nw,
                                                 const float* __restrict__ nb,
                                                 float* __restrict__ xh){
    int bl = blockIdx.x, d = threadIdx.x;
    float val = x[(size_t)bl*DM + d];
    __shared__ float red[4];
    float v = val;
    for (int o=32;o>0;o>>=1) v += __shfl_down(v, o, 64);
    if ((d&63)==0) red[d>>6] = v;
    __syncthreads();
    float mu = (red[0]+red[1]+red[2]+red[3])*(1.f/256.f);
    __syncthreads();
    float diff = val - mu;
    v = diff*diff;
    for (int o=32;o>0;o>>=1) v += __shfl_down(v, o, 64);
    if ((d&63)==0) red[d>>6] = v;
    __syncthreads();
    float var = (red[0]+red[1]+red[2]+red[3])*(1.f/256.f);
    xh[(size_t)bl*DM + d] = diff*rsqrtf(var+1e-5f)*nw[d] + nb[d];
}

// ---------------- column sums over l ----------------
__global__ __launch_bounds__(256) void colsum_kernel(const float* __restrict__ xh,
                                                     float* __restrict__ colsum){
    int b = blockIdx.x, chunk = blockIdx.y, d = threadIdx.x;
    float s = 0.f;
    for (int l = chunk*128; l < (chunk+1)*128; l++)
        s += xh[((size_t)b*LL + l)*DM + d];
    atomicAdd(&colsum[b*DM + d], s);
}

// ---------------- g = gelu(xh - colmean) ----------------
__global__ __launch_bounds__(256) void gelu_sub_kernel(const float* __restrict__ xh,
                                                       const float* __restrict__ colsum,
                                                       float* __restrict__ g){
    int bl = blockIdx.x, d = threadIdx.x;
    int b = bl / LL;
    float v = xh[(size_t)bl*DM + d] - colsum[b*DM + d]*(1.f/1024.f);
    g[(size_t)bl*DM + d] = gelu_f(v);
}

// ---------------- final projection ----------------
__global__ __launch_bounds__(256) void proj_kernel(const float* __restrict__ g,
                                                   const float* __restrict__ pw,
                                                   const float* __restrict__ pb,
                                                   float* __restrict__ out){
    int b = blockIdx.x, c = blockIdx.y, ch = blockIdx.z;
    int tid = threadIdx.x;
    const size_t F = (size_t)LL*DM;
    size_t base = ch*(F/16);
    float s = 0.f;
    for (size_t i = tid; i < F/16; i += 256)
        s += g[(size_t)b*F + base + i] * pw[(size_t)c*F + base + i];
    for (int o=32;o>0;o>>=1) s += __shfl_down(s, o, 64);
    __shared__ float red[4];
    if ((tid&63)==0) red[tid>>6] = s;
    __syncthreads();
    if (tid==0){
        float tot = red[0]+red[1]+red[2]+red[3];
        if (ch==0) tot += pb[c];
        atomicAdd(&out[b*3 + c], tot);
    }
}

extern "C" void kernel_launch(void* const* d_in, const int* in_sizes, int n_in,
                              void* d_out, int out_size, void* d_ws, size_t ws_size,
                              hipStream_t stream) {
    const float* x_enc   = (const float*)d_in[0];
    const float* token_w = (const float*)d_in[1];
    const float* qw = (const float*)d_in[2];
    const float* qb = (const float*)d_in[3];
    const float* kw = (const float*)d_in[4];
    const float* kb = (const float*)d_in[5];
    const float* vw = (const float*)d_in[6];
    const float* vb = (const float*)d_in[7];
    const float* ow = (const float*)d_in[8];
    const float* ob = (const float*)d_in[9];
    const float* c1w = (const float*)d_in[10];
    const float* c2w = (const float*)d_in[11];
    const float* norm_w = (const float*)d_in[12];
    const float* norm_b = (const float*)d_in[13];
    const float* proj_w = (const float*)d_in[14];
    const float* proj_b = (const float*)d_in[15];
    float* outp = (float*)d_out;

    const size_t NTOK = (size_t)BB*LL*DM;        // 8388608
    float* ws = (float*)d_ws;
    float* buf0 = ws;
    float* buf1 = ws + NTOK;
    float* buf2 = ws + 2*NTOK;
    ushort* wu = (ushort*)(ws + 3*NTOK);
    const size_t WSM = (size_t)NLAYERS*DM*DM;    // 196608
    const size_t WSF = (size_t)NLAYERS*DFF*DM;   // 786432
    ushort* qwh = wu;            ushort* qwl = qwh + WSM;
    ushort* kwh = qwl + WSM;     ushort* kwl = kwh + WSM;
    ushort* vwh = kwl + WSM;     ushort* vwl = vwh + WSM;
    ushort* owh = vwl + WSM;     ushort* owl = owh + WSM;
    ushort* c1wh = owl + WSM;    ushort* c1wl = c1wh + WSF;
    ushort* c2wh = c1wl + WSF;   ushort* c2wl = c2wh + WSF;
    // total: 8*WSM + 4*WSF = 1572864 + 3145728 = 4718592 ushorts = 2359296 floats
    float* after_w = ws + 3*NTOK + 2359296;
    float* mc     = after_w;
    float* colsum = mc + (size_t)BB*LL;
    int*   delays = (int*)(colsum + BB*DM);
    float* wts    = (float*)(delays + BB*TOPK);

    hipMemsetAsync(d_out, 0, 96*sizeof(float), stream);

    {
        int n1 = NLAYERS*DM*DM;
        int n2 = NLAYERS*DFF*DM;
        split_w_k<<<(n1+255)/256, 256, 0, stream>>>(qw, qwh, qwl, n1);
        split_w_k<<<(n1+255)/256, 256, 0, stream>>>(kw, kwh, kwl, n1);
        split_w_k<<<(n1+255)/256, 256, 0, stream>>>(vw, vwh, vwl, n1);
        split_w_k<<<(n1+255)/256, 256, 0, stream>>>(ow, owh, owl, n1);
        split_w_k<<<(n2+255)/256, 256, 0, stream>>>(c1w, c1wh, c1wl, n2);
        split_w_k<<<(n2+255)/256, 256, 0, stream>>>(c2w, c2wh, c2wl, n2);
    }

    token_embed_k<<<BB*LL, 256, 0, stream>>>(x_enc, token_w, buf0);

    const int M = BB*LL;  // 32768
    const int FFNC = 8192; // rows per FFN chunk (y split pair fits exactly in buf0)

    for (int l=0; l<NLAYERS; l++){
        ushort* qwh_l = qwh + (size_t)l*DM*DM;  ushort* qwl_l = qwl + (size_t)l*DM*DM;
        ushort* kwh_l = kwh + (size_t)l*DM*DM;  ushort* kwl_l = kwl + (size_t)l*DM*DM;
        ushort* vwh_l = vwh + (size_t)l*DM*DM;  ushort* vwl_l = vwl + (size_t)l*DM*DM;
        ushort* owh_l = owh + (size_t)l*DM*DM;  ushort* owl_l = owl + (size_t)l*DM*DM;
        ushort* c1wh_l = c1wh + (size_t)l*DFF*DM; ushort* c1wl_l = c1wl + (size_t)l*DFF*DM;
        ushort* c2wh_l = c2wh + (size_t)l*DM*DFF; ushort* c2wl_l = c2wl + (size_t)l*DM*DFF;
        const float* qb_l = qb + (size_t)l*DM;
        const float* kb_l = kb + (size_t)l*DM;
        const float* vb_l = vb + (size_t)l*DM;
        const float* ob_l = ob + (size_t)l*DM;

        // q -> buf1 split pair, k -> buf2 split pair
        ushort* qh_p = (ushort*)buf1;  ushort* ql_p = qh_p + NTOK;
        ushort* kh_p = (ushort*)buf2;  ushort* kl_p = kh_p + NTOK;
        gemm_mfma_split<0,true,false,2><<<(M/128)*(DM/128), 256, 0, stream>>>(
            buf0, nullptr, qwh_l, qwl_l, qb_l, qh_p, ql_p, M, DM, DM);
        gemm_mfma_split<0,true,false,2><<<(M/128)*(DM/128), 256, 0, stream>>>(
            buf0, nullptr, kwh_l, kwl_l, kb_l, kh_p, kl_p, M, DM, DM);

        hipMemsetAsync(mc, 0, (size_t)BB*LL*sizeof(float), stream);
        corr_mfma<<<dim3(LL/128, LL/128, BB), 256, 0, stream>>>(qh_p, ql_p, kh_p, kl_p, mc);
        topk_kernel<<<BB, 256, 0, stream>>>(mc, delays, wts);

        // v -> buf1 (f32), a -> buf2 (f32), o -> buf1 (f32)
        gemm_mfma_split<0,true,false,0><<<(M/128)*(DM/128), 256, 0, stream>>>(
            buf0, nullptr, vwh_l, vwl_l, vb_l, buf1, nullptr, M, DM, DM);
        attn_gather<<<BB*LL, 256, 0, stream>>>(buf1, delays, wts, buf2);
        gemm_mfma_split<0,true,false,0><<<(M/128)*(DM/128), 256, 0, stream>>>(
            buf2, nullptr, owh_l, owl_l, ob_l, buf1, nullptr, M, DM, DM);

        // x1 = (x + o) - movmean -> buf2 ; buf0 (x) dead after this
        add_decomp<<<dim3(BB, LL/32), 256, 0, stream>>>(buf0, buf1, buf2);

        // FFN chunked: y split pair in buf0; y2 -> buf1
        ushort* yh_p = (ushort*)buf0;
        ushort* yl_p = yh_p + (size_t)FFNC*DFF;
        for (int c0 = 0; c0 < M; c0 += FFNC){
            gemm_mfma_split<0,false,true,2><<<(FFNC/128)*(DFF/128), 256, 0, stream>>>(
                buf2 + (size_t)c0*DM, nullptr, c1wh_l, c1wl_l, nullptr, yh_p, yl_p, FFNC, DFF, DM);
            gemm_mfma_split<2,false,false,0><<<(FFNC/128)*(DM/128), 256, 0, stream>>>(
                yh_p, yl_p, c2wh_l, c2wl_l, nullptr, buf1 + (size_t)c0*DM, nullptr, FFNC, DM, DFF);
        }

        // x = (x1 + y2) - movmean -> buf0
        add_decomp<<<dim3(BB, LL/32), 256, 0, stream>>>(buf2, buf1, buf0);
    }

    ln_kernel<<<BB*LL, 256, 0, stream>>>(buf0, norm_w, norm_b, buf1);
    hipMemsetAsync(colsum, 0, (size_t)BB*DM*sizeof(float), stream);
    colsum_kernel<<<dim3(BB, 8), 256, 0, stream>>>(buf1, colsum);
    gelu_sub_kernel<<<BB*LL, 256, 0, stream>>>(buf1, colsum, buf2);
    proj_kernel<<<dim3(BB, 3, 16), 256, 0, stream>>>(buf2, proj_w, proj_b, outp);
}

// Round 7
// 2351.657 us; speedup vs baseline: 2.6021x; 1.2649x over previous
//
#include <hip/hip_runtime.h>
#include <hip/hip_bf16.h>
#include <math.h>

// Problem constants
#define BB 32
#define LL 1024
#define C_IN 21
#define DM 256
#define DFF 1024
#define NLAYERS 3
#define TOPK 6
#define LSCALE 4096.0f
#define LINV (1.0f/4096.0f)

typedef __attribute__((ext_vector_type(8))) short short8v;
typedef __attribute__((ext_vector_type(8))) _Float16 half8;
typedef __attribute__((ext_vector_type(4))) float f32x4;

__device__ __forceinline__ float gelu_f(float v){
    return 0.5f * v * (1.0f + erff(v * 0.7071067811865476f));
}
__device__ __forceinline__ ushort f2h_bits(float f){
    _Float16 h = (_Float16)f;
    return __builtin_bit_cast(ushort, h);
}

// ---------------- weight conversion: f16 hi + 4096*lo ----------------
__global__ __launch_bounds__(256) void split_w_k(const float* __restrict__ src,
                                                 ushort* __restrict__ h, ushort* __restrict__ l, int n){
    int i = blockIdx.x*256 + threadIdx.x;
    if (i < n){
        float f = src[i];
        _Float16 hh = (_Float16)f;
        h[i] = __builtin_bit_cast(ushort, hh);
        l[i] = f2h_bits((f - (float)hh) * LSCALE);
    }
}
// strided variant for building the concatenated [qw;kw] per-layer weight
__global__ __launch_bounds__(256) void split_w_strided(const float* __restrict__ src,
                                                       ushort* __restrict__ h, ushort* __restrict__ l,
                                                       int n, int src_ls, int dst_ls, int dst_off){
    int i = blockIdx.x*256 + threadIdx.x;
    if (i < n){
        int layer = i / src_ls, r = i % src_ls;
        float f = src[i];
        _Float16 hh = (_Float16)f;
        size_t d = (size_t)layer*dst_ls + dst_off + r;
        h[d] = __builtin_bit_cast(ushort, hh);
        l[d] = f2h_bits((f - (float)hh) * LSCALE);
    }
}
__global__ __launch_bounds__(256) void cat_bias_k(const float* __restrict__ b1,
                                                  const float* __restrict__ b2,
                                                  float* __restrict__ out, int n){ // n = 3*512
    int i = blockIdx.x*256 + threadIdx.x;
    if (i < n){
        int layer = i / 512, c = i % 512;
        out[i] = (c < 256) ? b1[layer*256 + c] : b2[layer*256 + c - 256];
    }
}

// ---------------- token embedding: circular conv1d k=3 ----------------
__global__ __launch_bounds__(256) void token_embed_k(const float* __restrict__ x,
                                                     const float* __restrict__ w,
                                                     float* __restrict__ out){
    int bl = blockIdx.x;
    int b = bl / LL, l = bl % LL;
    int d = threadIdx.x;
    __shared__ float xs[3][C_IN];
    if (threadIdx.x < 3*C_IN){
        int j = threadIdx.x / C_IN, c = threadIdx.x % C_IN;
        int ll = l + j - 1;
        ll = (ll + LL) % LL;
        xs[j][c] = x[(size_t)b*LL*C_IN + (size_t)ll*C_IN + c];
    }
    __syncthreads();
    const float* wd = w + (size_t)d*C_IN*3;
    float acc = 0.f;
    #pragma unroll
    for (int c=0;c<C_IN;c++){
        #pragma unroll
        for (int j=0;j<3;j++)
            acc += xs[j][c] * wd[c*3+j];
    }
    out[(size_t)bl*DM + d] = acc;
}

// =================== split-f16 MFMA GEMM, block 128x64, 4 waves of 64x32 ===================
// C(M,N) = A(M,K) @ W(N,K)^T [+bias] [gelu]
// AMODE: 0 = A f32 (split on the fly), 2 = A split pair (Av=hi, Av2=4096*lo)
// OMODE: 0 = f32 out (Cv), 2 = split pair out (Cv,C2v), 3 = qk dual split pair
//        (col<256 -> Cv/C2v at col; else -> C3v/C4v at col-256; out stride 256)
template<int AMODE, bool BIAS, bool GELU, int OMODE>
__global__ __launch_bounds__(256) void gemm_mfma_split(const void* __restrict__ Av,
                                                       const void* __restrict__ Av2,
                                                       const ushort* __restrict__ Wh,
                                                       const ushort* __restrict__ Wl,
                                                       const float* __restrict__ bias,
                                                       void* __restrict__ Cv,
                                                       void* __restrict__ C2v,
                                                       void* __restrict__ C3v,
                                                       void* __restrict__ C4v,
                                                       int M, int N, int K){
    __shared__ __align__(16) ushort Ah_s[128*32];
    __shared__ __align__(16) ushort Al_s[128*32];
    __shared__ __align__(16) ushort Wh_s[64*32];
    __shared__ __align__(16) ushort Wl_s[64*32];

    const int tid = threadIdx.x;
    const int MB = M >> 7;
    const int bx = blockIdx.x % MB, by = blockIdx.x / MB;
    const int bm = bx << 7, bn = by << 6;

    const int lane = tid & 63;
    const int wid  = tid >> 6;
    const int wm = wid >> 1, wn = wid & 1;   // waves: 2 (M) x 2 (N)
    const int lr = lane & 15, lg = lane >> 4;

    int aoff[4], boff[2];
    #pragma unroll
    for (int f=0; f<4; f++){
        int ar = wm*64 + f*16 + lr;
        aoff[f] = ar*32 + (lg ^ ((ar>>1)&3))*8;
    }
    #pragma unroll
    for (int g=0; g<2; g++){
        int br = wn*32 + g*16 + lr;
        boff[g] = br*32 + (lg ^ ((br>>1)&3))*8;
    }

    f32x4 acc[4][2], accX[4][2];
    #pragma unroll
    for (int i=0;i<4;i++)
        #pragma unroll
        for (int j=0;j<2;j++){
            acc[i][j]  = (f32x4){0.f,0.f,0.f,0.f};
            accX[i][j] = (f32x4){0.f,0.f,0.f,0.f};
        }

    for (int k0=0; k0<K; k0+=32){
        // ---- stage A (128 rows, 2 passes) ----
        #pragma unroll
        for (int i=0;i<2;i++){
            int c = i*256 + tid;
            int row = c >> 2, ko = c & 3;
            int sw = ko ^ ((row>>1)&3);
            int dst = row*32 + sw*8;
            if (AMODE == 2){
                const ushort* Ah_g = (const ushort*)Av;
                const ushort* Al_g = (const ushort*)Av2;
                size_t src = (size_t)(bm+row)*K + k0 + ko*8;
                *reinterpret_cast<short8v*>(&Ah_s[dst]) = *reinterpret_cast<const short8v*>(Ah_g + src);
                *reinterpret_cast<short8v*>(&Al_s[dst]) = *reinterpret_cast<const short8v*>(Al_g + src);
            } else {
                const float* A = (const float*)Av;
                const float* p = A + (size_t)(bm+row)*K + k0 + ko*8;
                float4 f0 = *reinterpret_cast<const float4*>(p);
                float4 f1 = *reinterpret_cast<const float4*>(p+4);
                float vals[8] = {f0.x,f0.y,f0.z,f0.w,f1.x,f1.y,f1.z,f1.w};
                short8v hv, lv;
                #pragma unroll
                for (int j=0;j<8;j++){
                    _Float16 hh = (_Float16)vals[j];
                    hv[j] = (short)__builtin_bit_cast(ushort, hh);
                    lv[j] = (short)f2h_bits((vals[j] - (float)hh) * LSCALE);
                }
                *reinterpret_cast<short8v*>(&Ah_s[dst]) = hv;
                *reinterpret_cast<short8v*>(&Al_s[dst]) = lv;
            }
        }
        // ---- stage W (64 rows, 1 pass) ----
        {
            int row = tid >> 2, ko = tid & 3;
            int sw = ko ^ ((row>>1)&3);
            int dst = row*32 + sw*8;
            size_t src = (size_t)(bn+row)*K + k0 + ko*8;
            *reinterpret_cast<short8v*>(&Wh_s[dst]) = *reinterpret_cast<const short8v*>(Wh + src);
            *reinterpret_cast<short8v*>(&Wl_s[dst]) = *reinterpret_cast<const short8v*>(Wl + src);
        }
        __syncthreads();

        short8v af[4], al[4], bf_[2], bl[2];
        #pragma unroll
        for (int f=0; f<4; f++){
            af[f] = *reinterpret_cast<short8v*>(&Ah_s[aoff[f]]);
            al[f] = *reinterpret_cast<short8v*>(&Al_s[aoff[f]]);
        }
        #pragma unroll
        for (int g=0; g<2; g++){
            bf_[g] = *reinterpret_cast<short8v*>(&Wh_s[boff[g]]);
            bl[g]  = *reinterpret_cast<short8v*>(&Wl_s[boff[g]]);
        }
        #pragma unroll
        for (int i=0;i<4;i++){
            #pragma unroll
            for (int j=0;j<2;j++){
                acc[i][j] = __builtin_amdgcn_mfma_f32_16x16x32_f16(
                    __builtin_bit_cast(half8, af[i]), __builtin_bit_cast(half8, bf_[j]), acc[i][j], 0,0,0);
                accX[i][j] = __builtin_amdgcn_mfma_f32_16x16x32_f16(
                    __builtin_bit_cast(half8, af[i]), __builtin_bit_cast(half8, bl[j]), accX[i][j], 0,0,0);
                accX[i][j] = __builtin_amdgcn_mfma_f32_16x16x32_f16(
                    __builtin_bit_cast(half8, al[i]), __builtin_bit_cast(half8, bf_[j]), accX[i][j], 0,0,0);
            }
        }
        __syncthreads();
    }

    // ---- epilogue ----
    const int crow0 = bm + wm*64, ccol0 = bn + wn*32;
    #pragma unroll
    for (int i=0;i<4;i++){
        #pragma unroll
        for (int j=0;j<2;j++){
            int row0 = crow0 + i*16 + lg*4;
            int col  = ccol0 + j*16 + lr;
            float bv = BIAS ? bias[col] : 0.f;
            #pragma unroll
            for (int r=0;r<4;r++){
                float v = acc[i][j][r] + accX[i][j][r]*LINV + bv;
                if (GELU) v = gelu_f(v);
                if (OMODE == 0){
                    ((float*)Cv)[(size_t)(row0+r)*N + col] = v;
                } else if (OMODE == 2){
                    size_t idx = (size_t)(row0+r)*N + col;
                    _Float16 hh = (_Float16)v;
                    ((ushort*)Cv)[idx]  = __builtin_bit_cast(ushort, hh);
                    ((ushort*)C2v)[idx] = f2h_bits((v - (float)hh) * LSCALE);
                } else { // OMODE 3: qk dual pair, out stride 256
                    _Float16 hh = (_Float16)v;
                    ushort hb = __builtin_bit_cast(ushort, hh);
                    ushort lb = f2h_bits((v - (float)hh) * LSCALE);
                    if (col < 256){
                        size_t idx = (size_t)(row0+r)*256 + col;
                        ((ushort*)Cv)[idx]  = hb;
                        ((ushort*)C2v)[idx] = lb;
                    } else {
                        size_t idx = (size_t)(row0+r)*256 + (col-256);
                        ((ushort*)C3v)[idx] = hb;
                        ((ushort*)C4v)[idx] = lb;
                    }
                }
            }
        }
    }
}

// =================== corr: Q-tile 128 x K-tile 64, XCD-swizzled 1D grid ===================
__global__ __launch_bounds__(256) void corr_mfma(const ushort* __restrict__ qh,
                                                 const ushort* __restrict__ ql,
                                                 const ushort* __restrict__ kh,
                                                 const ushort* __restrict__ kl,
                                                 float* __restrict__ mc){
    __shared__ __align__(16) ushort Qh_s[128*32];
    __shared__ __align__(16) ushort Ql_s[128*32];
    __shared__ __align__(16) ushort Kh_s[64*32];
    __shared__ __align__(16) ushort Kl_s[64*32];
    __shared__ float bins[191];

    const int tid = threadIdx.x;
    // XCD-aware swizzle: 4096 blocks, 8 XCDs -> contiguous 512-block chunks per XCD
    int flat = blockIdx.x;
    flat = (flat & 7) * 512 + (flat >> 3);
    const int bxt = flat & 7;          // Q tile (8)
    const int byt = (flat >> 3) & 15;  // K tile (16)
    const int b   = flat >> 7;         // batch (32)
    const int bi = bxt * 128, bj = byt * 64;

    for (int i=tid; i<191; i+=256) bins[i] = 0.f;

    const int lane = tid & 63;
    const int wid  = tid >> 6;
    const int wm = wid >> 1, wn = wid & 1;
    const int lr = lane & 15, lg = lane >> 4;

    int aoff[4], boff[2];
    #pragma unroll
    for (int f=0; f<4; f++){
        int ar = wm*64 + f*16 + lr;
        aoff[f] = ar*32 + (lg ^ ((ar>>1)&3))*8;
    }
    #pragma unroll
    for (int g=0; g<2; g++){
        int br = wn*32 + g*16 + lr;
        boff[g] = br*32 + (lg ^ ((br>>1)&3))*8;
    }

    f32x4 acc[4][2], accX[4][2];
    #pragma unroll
    for (int i=0;i<4;i++)
        #pragma unroll
        for (int j=0;j<2;j++){
            acc[i][j]  = (f32x4){0.f,0.f,0.f,0.f};
            accX[i][j] = (f32x4){0.f,0.f,0.f,0.f};
        }

    const size_t qbase = (size_t)b*LL*DM;

    for (int k0=0; k0<DM; k0+=32){
        #pragma unroll
        for (int i=0;i<2;i++){
            int c = i*256 + tid;
            int row = c >> 2, ko = c & 3;
            int sw = ko ^ ((row>>1)&3);
            int dst = row*32 + sw*8;
            size_t qsrc = qbase + (size_t)(bi+row)*DM + k0 + ko*8;
            *reinterpret_cast<short8v*>(&Qh_s[dst]) = *reinterpret_cast<const short8v*>(qh + qsrc);
            *reinterpret_cast<short8v*>(&Ql_s[dst]) = *reinterpret_cast<const short8v*>(ql + qsrc);
        }
        {
            int row = tid >> 2, ko = tid & 3;
            int sw = ko ^ ((row>>1)&3);
            int dst = row*32 + sw*8;
            size_t ksrc = qbase + (size_t)(bj+row)*DM + k0 + ko*8;
            *reinterpret_cast<short8v*>(&Kh_s[dst]) = *reinterpret_cast<const short8v*>(kh + ksrc);
            *reinterpret_cast<short8v*>(&Kl_s[dst]) = *reinterpret_cast<const short8v*>(kl + ksrc);
        }
        __syncthreads();

        short8v ah[4], al_[4], bh[2], bl_[2];
        #pragma unroll
        for (int f=0; f<4; f++){
            ah[f]  = *reinterpret_cast<short8v*>(&Qh_s[aoff[f]]);
            al_[f] = *reinterpret_cast<short8v*>(&Ql_s[aoff[f]]);
        }
        #pragma unroll
        for (int g=0; g<2; g++){
            bh[g]  = *reinterpret_cast<short8v*>(&Kh_s[boff[g]]);
            bl_[g] = *reinterpret_cast<short8v*>(&Kl_s[boff[g]]);
        }
        #pragma unroll
        for (int i=0;i<4;i++){
            #pragma unroll
            for (int j=0;j<2;j++){
                acc[i][j] = __builtin_amdgcn_mfma_f32_16x16x32_f16(
                    __builtin_bit_cast(half8, ah[i]), __builtin_bit_cast(half8, bh[j]), acc[i][j], 0,0,0);
                accX[i][j] = __builtin_amdgcn_mfma_f32_16x16x32_f16(
                    __builtin_bit_cast(half8, ah[i]), __builtin_bit_cast(half8, bl_[j]), accX[i][j], 0,0,0);
                accX[i][j] = __builtin_amdgcn_mfma_f32_16x16x32_f16(
                    __builtin_bit_cast(half8, al_[i]), __builtin_bit_cast(half8, bh[j]), accX[i][j], 0,0,0);
            }
        }
        __syncthreads();
    }

    // diagonal binning: d_local = row - col in [-63,127] -> bins[d+63]
    #pragma unroll
    for (int i=0;i<4;i++){
        #pragma unroll
        for (int j=0;j<2;j++){
            int rbase = wm*64 + i*16 + lg*4;
            int col   = wn*32 + j*16 + lr;
            #pragma unroll
            for (int r=0;r<4;r++){
                float g = acc[i][j][r] + accX[i][j][r] * LINV;
                atomicAdd(&bins[(rbase + r) - col + 63], g);
            }
        }
    }
    __syncthreads();
    for (int i=tid; i<191; i+=256){
        int t = ((bi - bj + i - 63) % LL + LL) & (LL-1);
        atomicAdd(&mc[(size_t)b*LL + t], bins[i] * (1.f/256.f));
    }
}

// ---------------- top-6 + softmax per batch ----------------
__global__ __launch_bounds__(256) void topk_kernel(const float* __restrict__ mc,
                                                   int* __restrict__ delays,
                                                   float* __restrict__ wts){
    int b = blockIdx.x, tid = threadIdx.x;
    __shared__ float sv[LL];
    __shared__ float rv[256];
    __shared__ int ri[256];
    __shared__ float topv[TOPK];
    __shared__ int topi[TOPK];
    for (int i=tid;i<LL;i+=256) sv[i] = mc[(size_t)b*LL + i];
    __syncthreads();
    for (int it=0; it<TOPK; it++){
        float best = -1e30f; int bi = LL;
        for (int i=tid;i<LL;i+=256){
            float v = sv[i];
            if (v > best || (v == best && i < bi)){ best = v; bi = i; }
        }
        rv[tid]=best; ri[tid]=bi;
        __syncthreads();
        for (int s=128;s>0;s>>=1){
            if (tid < s){
                if (rv[tid+s] > rv[tid] || (rv[tid+s]==rv[tid] && ri[tid+s]<ri[tid])){
                    rv[tid]=rv[tid+s]; ri[tid]=ri[tid+s];
                }
            }
            __syncthreads();
        }
        if (tid==0){ topv[it]=rv[0]; topi[it]=ri[0]; sv[ri[0]] = -1e30f; }
        __syncthreads();
    }
    if (tid==0){
        float mx = topv[0];
        float e[TOPK], se=0.f;
        for (int kk=0;kk<TOPK;kk++){ e[kk]=expf(topv[kk]-mx); se+=e[kk]; }
        for (int kk=0;kk<TOPK;kk++){
            wts[b*TOPK+kk] = e[kk]/se;
            delays[b*TOPK+kk] = topi[kk];
        }
    }
}

// ---------------- attention gather (float4) ----------------
__global__ __launch_bounds__(256) void attn_gather4(const float4* __restrict__ v,
                                                    const int* __restrict__ delays,
                                                    const float* __restrict__ wts,
                                                    float4* __restrict__ a){
    int gid = blockIdx.x*256 + threadIdx.x;
    int d4 = gid & 63;
    int bl = gid >> 6;
    int b = bl >> 10, l = bl & (LL-1);
    const int* dl = delays + b*TOPK;
    const float* w = wts + b*TOPK;
    float ax=0.f, ay=0.f, az=0.f, aw=0.f;
    #pragma unroll
    for (int kk=0;kk<TOPK;kk++){
        int ls = (l + dl[kk]) & (LL-1);
        float4 t = v[(size_t)((b<<10)+ls)*64 + d4];
        float wk = w[kk];
        ax += wk*t.x; ay += wk*t.y; az += wk*t.z; aw += wk*t.w;
    }
    a[gid] = make_float4(ax, ay, az, aw);
}

// ---------------- out = (xa+xb) - movmean5(xa+xb), clamped edges (float4 rolling) ----------------
__global__ __launch_bounds__(256) void add_decomp4(const float4* __restrict__ xa,
                                                   const float4* __restrict__ xb,
                                                   float4* __restrict__ out){
    int d4 = threadIdx.x & 63;
    int rg = threadIdx.x >> 6;
    int b = blockIdx.x;
    int l0 = blockIdx.y*128 + rg*32;
    float4 win[5];
    #pragma unroll
    for (int i=0;i<4;i++){
        int g = l0 - 2 + i;
        g = g < 0 ? 0 : g;
        size_t idx = (size_t)((b<<10) + g)*64 + d4;
        float4 A = xa[idx], Bv = xb[idx];
        win[i] = make_float4(A.x+Bv.x, A.y+Bv.y, A.z+Bv.z, A.w+Bv.w);
    }
    for (int i=0;i<32;i++){
        int g = l0 + 2 + i;
        g = g > LL-1 ? LL-1 : g;
        size_t idx = (size_t)((b<<10) + g)*64 + d4;
        float4 A = xa[idx], Bv = xb[idx];
        win[4] = make_float4(A.x+Bv.x, A.y+Bv.y, A.z+Bv.z, A.w+Bv.w);
        float4 o;
        o.x = win[2].x - (win[0].x+win[1].x+win[2].x+win[3].x+win[4].x)*0.2f;
        o.y = win[2].y - (win[0].y+win[1].y+win[2].y+win[3].y+win[4].y)*0.2f;
        o.z = win[2].z - (win[0].z+win[1].z+win[2].z+win[3].z+win[4].z)*0.2f;
        o.w = win[2].w - (win[0].w+win[1].w+win[2].w+win[3].w+win[4].w)*0.2f;
        out[(size_t)((b<<10) + l0 + i)*64 + d4] = o;
        win[0]=win[1]; win[1]=win[2]; win[2]=win[3]; win[3]=win[4];
    }
}

// ---------------- layernorm over d per (b,l) ----------------
__global__ __launch_bounds__(256) void ln_kernel(const float* __restrict__ x,
                                                 const float* __restrict__ nw,
                                                 const float* __restrict__ nb,
                                                 float* __restrict__ xh){
    int bl = blockIdx.x, d = threadIdx.x;
    float val = x[(size_t)bl*DM + d];
    __shared__ float red[4];
    float v = val;
    for (int o=32;o>0;o>>=1) v += __shfl_down(v, o, 64);
    if ((d&63)==0) red[d>>6] = v;
    __syncthreads();
    float mu = (red[0]+red[1]+red[2]+red[3])*(1.f/256.f);
    __syncthreads();
    float diff = val - mu;
    v = diff*diff;
    for (int o=32;o>0;o>>=1) v += __shfl_down(v, o, 64);
    if ((d&63)==0) red[d>>6] = v;
    __syncthreads();
    float var = (red[0]+red[1]+red[2]+red[3])*(1.f/256.f);
    xh[(size_t)bl*DM + d] = diff*rsqrtf(var+1e-5f)*nw[d] + nb[d];
}

// ---------------- column sums over l ----------------
__global__ __launch_bounds__(256) void colsum_kernel(const float* __restrict__ xh,
                                                     float* __restrict__ colsum){
    int b = blockIdx.x, chunk = blockIdx.y, d = threadIdx.x;
    float s = 0.f;
    for (int l = chunk*128; l < (chunk+1)*128; l++)
        s += xh[((size_t)b*LL + l)*DM + d];
    atomicAdd(&colsum[b*DM + d], s);
}

// ---------------- g = gelu(xh - colmean) ----------------
__global__ __launch_bounds__(256) void gelu_sub_kernel(const float* __restrict__ xh,
                                                       const float* __restrict__ colsum,
                                                       float* __restrict__ g){
    int bl = blockIdx.x, d = threadIdx.x;
    int b = bl / LL;
    float v = xh[(size_t)bl*DM + d] - colsum[b*DM + d]*(1.f/1024.f);
    g[(size_t)bl*DM + d] = gelu_f(v);
}

// ---------------- final projection ----------------
__global__ __launch_bounds__(256) void proj_kernel(const float* __restrict__ g,
                                                   const float* __restrict__ pw,
                                                   const float* __restrict__ pb,
                                                   float* __restrict__ out){
    int b = blockIdx.x, c = blockIdx.y, ch = blockIdx.z;
    int tid = threadIdx.x;
    const size_t F = (size_t)LL*DM;
    size_t base = ch*(F/16);
    float s = 0.f;
    for (size_t i = tid; i < F/16; i += 256)
        s += g[(size_t)b*F + base + i] * pw[(size_t)c*F + base + i];
    for (int o=32;o>0;o>>=1) s += __shfl_down(s, o, 64);
    __shared__ float red[4];
    if ((tid&63)==0) red[tid>>6] = s;
    __syncthreads();
    if (tid==0){
        float tot = red[0]+red[1]+red[2]+red[3];
        if (ch==0) tot += pb[c];
        atomicAdd(&out[b*3 + c], tot);
    }
}

extern "C" void kernel_launch(void* const* d_in, const int* in_sizes, int n_in,
                              void* d_out, int out_size, void* d_ws, size_t ws_size,
                              hipStream_t stream) {
    const float* x_enc   = (const float*)d_in[0];
    const float* token_w = (const float*)d_in[1];
    const float* qw = (const float*)d_in[2];
    const float* qb = (const float*)d_in[3];
    const float* kw = (const float*)d_in[4];
    const float* kb = (const float*)d_in[5];
    const float* vw = (const float*)d_in[6];
    const float* vb = (const float*)d_in[7];
    const float* ow = (const float*)d_in[8];
    const float* ob = (const float*)d_in[9];
    const float* c1w = (const float*)d_in[10];
    const float* c2w = (const float*)d_in[11];
    const float* norm_w = (const float*)d_in[12];
    const float* norm_b = (const float*)d_in[13];
    const float* proj_w = (const float*)d_in[14];
    const float* proj_b = (const float*)d_in[15];
    float* outp = (float*)d_out;

    const size_t NTOK = (size_t)BB*LL*DM;        // 8388608
    float* ws = (float*)d_ws;
    float* buf0 = ws;
    float* buf1 = ws + NTOK;
    float* buf2 = ws + 2*NTOK;
    ushort* wu = (ushort*)(ws + 3*NTOK);
    const size_t WSM = (size_t)NLAYERS*DM*DM;    // 196608
    const size_t WSF = (size_t)NLAYERS*DFF*DM;   // 786432
    // qk combined: [3][512][256] hi+lo = 2*2*WSM
    ushort* qkwh = wu;             ushort* qkwl = qkwh + 2*WSM;
    ushort* vwh  = qkwl + 2*WSM;   ushort* vwl  = vwh + WSM;
    ushort* owh  = vwl + WSM;      ushort* owl  = owh + WSM;
    ushort* c1wh = owl + WSM;      ushort* c1wl = c1wh + WSF;
    ushort* c2wh = c1wl + WSF;     ushort* c2wl = c2wh + WSF;
    // total ushorts: 8*WSM + 4*WSF = 4718592 -> 2359296 floats
    float* after_w = ws + 3*NTOK + 2359296;
    float* qkbias = after_w;                      // 3*512
    float* mc     = qkbias + (size_t)NLAYERS*512;
    float* colsum = mc + (size_t)BB*LL;
    int*   delays = (int*)(colsum + BB*DM);
    float* wts    = (float*)(delays + BB*TOPK);

    hipMemsetAsync(d_out, 0, 96*sizeof(float), stream);

    {
        int n1 = NLAYERS*DM*DM;      // 196608
        int n2 = NLAYERS*DFF*DM;     // 786432
        // qk combined weights: q -> dst_off 0, k -> dst_off 65536, layer stride 131072
        split_w_strided<<<(n1+255)/256, 256, 0, stream>>>(qw, qkwh, qkwl, n1, 65536, 131072, 0);
        split_w_strided<<<(n1+255)/256, 256, 0, stream>>>(kw, qkwh, qkwl, n1, 65536, 131072, 65536);
        cat_bias_k<<<(NLAYERS*512+255)/256, 256, 0, stream>>>(qb, kb, qkbias, NLAYERS*512);
        split_w_k<<<(n1+255)/256, 256, 0, stream>>>(vw, vwh, vwl, n1);
        split_w_k<<<(n1+255)/256, 256, 0, stream>>>(ow, owh, owl, n1);
        split_w_k<<<(n2+255)/256, 256, 0, stream>>>(c1w, c1wh, c1wl, n2);
        split_w_k<<<(n2+255)/256, 256, 0, stream>>>(c2w, c2wh, c2wl, n2);
    }

    token_embed_k<<<BB*LL, 256, 0, stream>>>(x_enc, token_w, buf0);

    const int M = BB*LL;  // 32768
    const int FFNC = 8192;

    for (int l=0; l<NLAYERS; l++){
        ushort* qkwh_l = qkwh + (size_t)l*512*DM;  ushort* qkwl_l = qkwl + (size_t)l*512*DM;
        ushort* vwh_l = vwh + (size_t)l*DM*DM;     ushort* vwl_l = vwl + (size_t)l*DM*DM;
        ushort* owh_l = owh + (size_t)l*DM*DM;     ushort* owl_l = owl + (size_t)l*DM*DM;
        ushort* c1wh_l = c1wh + (size_t)l*DFF*DM;  ushort* c1wl_l = c1wl + (size_t)l*DFF*DM;
        ushort* c2wh_l = c2wh + (size_t)l*DM*DFF;  ushort* c2wl_l = c2wl + (size_t)l*DM*DFF;
        const float* qkb_l = qkbias + (size_t)l*512;
        const float* vb_l = vb + (size_t)l*DM;
        const float* ob_l = ob + (size_t)l*DM;

        // fused q+k -> buf1 pair (q), buf2 pair (k)
        ushort* qh_p = (ushort*)buf1;  ushort* ql_p = qh_p + NTOK;
        ushort* kh_p = (ushort*)buf2;  ushort* kl_p = kh_p + NTOK;
        gemm_mfma_split<0,true,false,3><<<(M/128)*(512/64), 256, 0, stream>>>(
            buf0, nullptr, qkwh_l, qkwl_l, qkb_l, qh_p, ql_p, kh_p, kl_p, M, 512, DM);

        hipMemsetAsync(mc, 0, (size_t)BB*LL*sizeof(float), stream);
        corr_mfma<<<4096, 256, 0, stream>>>(qh_p, ql_p, kh_p, kl_p, mc);
        topk_kernel<<<BB, 256, 0, stream>>>(mc, delays, wts);

        // v -> buf1 (f32), a -> buf2 (f32), o -> buf1 (f32)
        gemm_mfma_split<0,true,false,0><<<(M/128)*(DM/64), 256, 0, stream>>>(
            buf0, nullptr, vwh_l, vwl_l, vb_l, buf1, nullptr, nullptr, nullptr, M, DM, DM);
        attn_gather4<<<(BB*LL*64)/256, 256, 0, stream>>>(
            (const float4*)buf1, delays, wts, (float4*)buf2);
        gemm_mfma_split<0,true,false,0><<<(M/128)*(DM/64), 256, 0, stream>>>(
            buf2, nullptr, owh_l, owl_l, ob_l, buf1, nullptr, nullptr, nullptr, M, DM, DM);

        // x1 = (x + o) - movmean -> buf2 ; buf0 (x) dead after this
        add_decomp4<<<dim3(BB, LL/128), 256, 0, stream>>>(
            (const float4*)buf0, (const float4*)buf1, (float4*)buf2);

        // FFN chunked: y split pair in buf0; y2 -> buf1
        ushort* yh_p = (ushort*)buf0;
        ushort* yl_p = yh_p + (size_t)FFNC*DFF;
        for (int c0 = 0; c0 < M; c0 += FFNC){
            gemm_mfma_split<0,false,true,2><<<(FFNC/128)*(DFF/64), 256, 0, stream>>>(
                buf2 + (size_t)c0*DM, nullptr, c1wh_l, c1wl_l, nullptr, yh_p, yl_p, nullptr, nullptr, FFNC, DFF, DM);
            gemm_mfma_split<2,false,false,0><<<(FFNC/128)*(DM/64), 256, 0, stream>>>(
                yh_p, yl_p, c2wh_l, c2wl_l, nullptr, buf1 + (size_t)c0*DM, nullptr, nullptr, nullptr, FFNC, DM, DFF);
        }

        // x = (x1 + y2) - movmean -> buf0
        add_decomp4<<<dim3(BB, LL/128), 256, 0, stream>>>(
            (const float4*)buf2, (const float4*)buf1, (float4*)buf0);
    }

    ln_kernel<<<BB*LL, 256, 0, stream>>>(buf0, norm_w, norm_b, buf1);
    hipMemsetAsync(colsum, 0, (size_t)BB*DM*sizeof(float), stream);
    colsum_kernel<<<dim3(BB, 8), 256, 0, stream>>>(buf1, colsum);
    gelu_sub_kernel<<<BB*LL, 256, 0, stream>>>(buf1, colsum, buf2);
    proj_kernel<<<dim3(BB, 3, 16), 256, 0, stream>>>(buf2, proj_w, proj_b, outp);
}